// Round 2
// baseline (684.392 us; speedup 1.0000x reference)
//
#include <hip/hip_runtime.h>

typedef __attribute__((ext_vector_type(8))) short short8;
typedef __attribute__((ext_vector_type(16))) float f32x16;

// 5 LDS planes of 8192 B (64 rows x 128 B). Split pairs are always adjacent
// planes (lo = hi + 8192). No inter-plane pad: hi/lo same-bank is only ever a
// 2-way conflict within one instruction, which is free on CDNA4.
#define PP0 0
#define PP1 8192
#define PP2 16384
#define PP3 24576
#define PP4 32768

#define MFMA32(a, b, c) __builtin_amdgcn_mfma_f32_32x32x16_bf16((a), (b), (c), 0, 0, 0)

__device__ __forceinline__ int swadr(int m, int kc) {
  return m * 128 + ((kc ^ (m & 7)) << 4);
}
__device__ __forceinline__ unsigned cvtpk(float a, float b) {
  unsigned r;
  asm("v_cvt_pk_bf16_f32 %0, %1, %2" : "=v"(r) : "v"(a), "v"(b));
  return r;
}
__device__ __forceinline__ float dppswap(float v) {  // lane ^ 1
  return __int_as_float(
      __builtin_amdgcn_mov_dpp(__float_as_int(v), 0xB1, 0xF, 0xF, true));
}
__device__ __forceinline__ short8 ldf(const char* p, int off) {
  return *(const short8*)(p + off);
}

// ---- single-wave 64x64 matmul: C tiles {00,01,10,11}; SA/SB = operand split
// accumulate order per k-chunk: hh, (hl if SB), (lh if SA) — matches prior kernel
template <int OA, int OB, bool SA, bool SB>
__device__ __forceinline__ void mm64(f32x16& C0, f32x16& C1, f32x16& C2, f32x16& C3,
                                     const char* lds, const int (&pk)[4]) {
#pragma unroll
  for (int s = 0; s < 4; ++s) {
    short8 a0 = ldf(lds, pk[s] + OA);
    short8 a1 = ldf(lds, pk[s] + OA + 4096);
    short8 b0 = ldf(lds, pk[s] + OB);
    short8 b1 = ldf(lds, pk[s] + OB + 4096);
    C0 = MFMA32(a0, b0, C0);
    C1 = MFMA32(a0, b1, C1);
    C2 = MFMA32(a1, b0, C2);
    C3 = MFMA32(a1, b1, C3);
    if constexpr (SB) {
      short8 b0l = ldf(lds, pk[s] + OB + 8192);
      short8 b1l = ldf(lds, pk[s] + OB + 8192 + 4096);
      C0 = MFMA32(a0, b0l, C0);
      C1 = MFMA32(a0, b1l, C1);
      C2 = MFMA32(a1, b0l, C2);
      C3 = MFMA32(a1, b1l, C3);
    }
    if constexpr (SA) {
      short8 a0l = ldf(lds, pk[s] + OA + 8192);
      short8 a1l = ldf(lds, pk[s] + OA + 8192 + 4096);
      C0 = MFMA32(a0l, b0, C0);
      C1 = MFMA32(a0l, b1, C1);
      C2 = MFMA32(a1l, b0, C2);
      C3 = MFMA32(a1l, b1, C3);
    }
  }
}

// 32x32 both-split (drop lo*lo), single tile
template <int OA, int OB>
__device__ __forceinline__ void mm32(f32x16& C, const char* lds, const int (&pk)[4]) {
#pragma unroll
  for (int s = 0; s < 2; ++s) {
    short8 ah = ldf(lds, pk[s] + OA);
    short8 al = ldf(lds, pk[s] + OA + 8192);
    short8 bh = ldf(lds, pk[s] + OB);
    short8 bl = ldf(lds, pk[s] + OB + 8192);
    C = MFMA32(ah, bh, C);
    C = MFMA32(ah, bl, C);
    C = MFMA32(al, bh, C);
  }
}

__device__ __forceinline__ void z4(f32x16& C0, f32x16& C1, f32x16& C2, f32x16& C3) {
#pragma unroll
  for (int r = 0; r < 16; ++r) {
    C0[r] = 0.f; C1[r] = 0.f; C2[r] = 0.f; C3[r] = 0.f;
  }
}
// preload v*I into diagonal tiles (t=0,3), zero off-diagonal
__device__ __forceinline__ void pre4(f32x16& C0, f32x16& C1, f32x16& C2, f32x16& C3,
                                     const f32x16& dm, float v) {
#pragma unroll
  for (int r = 0; r < 16; ++r) {
    float d = v * dm[r];
    C0[r] = d; C3[r] = d; C1[r] = 0.f; C2[r] = 0.f;
  }
}
__device__ __forceinline__ void q16t(f32x16& v) {  // round regs to bf16 values
#pragma unroll
  for (int r = 0; r < 16; r += 2) {
    unsigned w = cvtpk(v[r], v[r + 1]);
    v[r] = __uint_as_float(w << 16);
    v[r + 1] = __uint_as_float(w & 0xFFFF0000u);
  }
}

// ---- full-matrix bf16-hi write: v = (SCALE? al*C : C) + (ADDI? be*I : 0)
template <int OFF, bool SCALE, bool ADDI>
__device__ __forceinline__ void wrhi64(char* lds, const int (&wo)[16], bool ev, int jd,
                                       const f32x16& C0, const f32x16& C1,
                                       const f32x16& C2, const f32x16& C3,
                                       const f32x16& dm, float al, float be) {
#pragma unroll
  for (int t = 0; t < 4; ++t) {
    const f32x16& C = t == 0 ? C0 : t == 1 ? C1 : t == 2 ? C2 : C3;
    const int base = OFF + (t >> 1) * 4096 + ((t & 1) ? jd : 0);
#pragma unroll
    for (int r = 0; r < 16; ++r) {
      float v = SCALE ? al * C[r] : C[r];
      if (ADDI && (t == 0 || t == 3)) v += be * dm[r];
      float vn = dppswap(v);
      unsigned hw = cvtpk(v, vn);
      if (ev) *(unsigned*)(lds + base + wo[r]) = hw;
    }
  }
}

// ---- full-matrix split write (hi plane OFF, lo plane OFF+8192)
template <int OFF>
__device__ __forceinline__ void wrsp64(char* lds, const int (&wo)[16], bool ev, int pl,
                                       int jd, const f32x16& C0, const f32x16& C1,
                                       const f32x16& C2, const f32x16& C3) {
#pragma unroll
  for (int t = 0; t < 4; ++t) {
    const f32x16& C = t == 0 ? C0 : t == 1 ? C1 : t == 2 ? C2 : C3;
    const int base = OFF + (t >> 1) * 4096 + ((t & 1) ? jd : 0) + pl;
#pragma unroll
    for (int r = 0; r < 16; ++r) {
      float v = C[r];
      float vn = dppswap(v);
      unsigned hw = cvtpk(v, vn);
      float lo = v - __uint_as_float(hw << 16);
      float lon = dppswap(lo);
      unsigned lw = cvtpk(lon, lo);
      *(unsigned*)(lds + base + wo[r]) = ev ? hw : lw;
    }
  }
}

template <int OFF>
__device__ __forceinline__ void wrsp32(char* lds, const int (&wo)[16], bool ev, int pl,
                                       const f32x16& C) {
  const int base = OFF + pl;
#pragma unroll
  for (int r = 0; r < 16; ++r) {
    float v = C[r];
    float vn = dppswap(v);
    unsigned hw = cvtpk(v, vn);
    float lo = v - __uint_as_float(hw << 16);
    float lon = dppswap(lo);
    unsigned lw = cvtpk(lon, lo);
    *(unsigned*)(lds + base + wo[r]) = ev ? hw : lw;
  }
}

__global__ void __launch_bounds__(64, 1)
spd_pool_kernel(const float* __restrict__ X, float* __restrict__ out) {
  // one wave per matrix; zero barriers (same-wave DS ops are in-order)
  __shared__ __align__(16) char lds[40960];

  const int lane = threadIdx.x;  // 0..63
  const int half = lane >> 5;
  const int ln31 = lane & 31;
  const bool ev = (ln31 & 1) == 0;
  const int pl = ev ? 0 : 8192;
  const int jd = half ? -64 : 64;  // C-write column-tile (j=1) offset delta

  // per-lane fragment-read bases (rows ln31; +4096 for row-tile i=1)
  int pk[4];
#pragma unroll
  for (int s = 0; s < 4; ++s) pk[s] = swadr(ln31, 2 * s + half);

  // per-lane C-write word offsets for tile (0,0); tile(i,j) = +4096i (+jd if j)
  int wo[16];
  {
    const int col0 = ln31 & ~1;
    const int cchunk = col0 >> 3, cbyte = (col0 & 7) * 2;
    const int rb = 4 * half;
#pragma unroll
    for (int r = 0; r < 16; ++r) {
      const int m = rb + (r & 3) + 8 * (r >> 2);
      wo[r] = m * 128 + ((cchunk ^ (m & 7)) << 4) + cbyte;
    }
  }
  // diag mask of the C fragment (valid for 64x64 diag tiles and 32x32)
  f32x16 dmask;
#pragma unroll
  for (int r = 0; r < 16; ++r)
    dmask[r] = ((r & 3) + 8 * (r >> 2) + 4 * half == ln31) ? 1.f : 0.f;

  // ======= init: P0/P1 = X' = X/6.6 (split); P2 = T0 = 1.5I - 0.5X' =======
  {
    const float ic1 = 1.0f / 6.6f;
    const float* Xg = X + (size_t)blockIdx.x * 4096;
    const int rr = lane >> 4;
    const int c0 = (lane & 15) * 4;
    const int kc = c0 >> 3;
    const int sub = (lane & 1) * 8;
#pragma unroll
    for (int k = 0; k < 16; ++k) {
      const int row = 4 * k + rr;
      float4 x = *(const float4*)(Xg + row * 64 + c0);
      float v0 = x.x * ic1, v1 = x.y * ic1, v2 = x.z * ic1, v3 = x.w * ic1;
      unsigned h0 = cvtpk(v0, v1), h1 = cvtpk(v2, v3);
      unsigned l0 = cvtpk(v0 - __uint_as_float(h0 << 16),
                          v1 - __uint_as_float(h0 & 0xFFFF0000u));
      unsigned l1 = cvtpk(v2 - __uint_as_float(h1 << 16),
                          v3 - __uint_as_float(h1 & 0xFFFF0000u));
      float t0 = ((row == c0) ? 1.5f : 0.f) - 0.5f * v0;
      float t1 = ((row == c0 + 1) ? 1.5f : 0.f) - 0.5f * v1;
      float t2 = ((row == c0 + 2) ? 1.5f : 0.f) - 0.5f * v2;
      float t3 = ((row == c0 + 3) ? 1.5f : 0.f) - 0.5f * v3;
      unsigned s0 = cvtpk(t0, t1), s1 = cvtpk(t2, t3);
      const int off = swadr(row, kc) + sub;
      *(uint2*)(lds + PP0 + off) = make_uint2(h0, h1);
      *(uint2*)(lds + PP1 + off) = make_uint2(l0, l1);
      *(uint2*)(lds + PP2 + off) = make_uint2(s0, s1);
    }
  }

  f32x16 Y0, Y1, Y2, Y3, Z0, Z1, Z2, Z3, A0, A1, A2, A3;

  // L1 it1: Y = X'h(P0) * T0(P2) -> P3 hi   [Z plane = P2 holds T0 = Z1]
  z4(Y0, Y1, Y2, Y3);
  mm64<PP0, PP2, false, false>(Y0, Y1, Y2, Y3, lds, pk);
  wrhi64<PP3, false, false>(lds, wo, ev, jd, Y0, Y1, Y2, Y3, dmask, 0.f, 0.f);

  // L1 bf16 iters 2..5: Z=P2, Y=P3, T=P4
#pragma unroll 1
  for (int it = 0; it < 4; ++it) {
    pre4(A0, A1, A2, A3, dmask, -3.f);
    mm64<PP2, PP3, false, false>(A0, A1, A2, A3, lds, pk);  // a = -3I + Z*Y
    wrhi64<PP4, true, false>(lds, wo, ev, jd, A0, A1, A2, A3, dmask, -0.5f, 0.f);
    z4(Y0, Y1, Y2, Y3);
    mm64<PP3, PP4, false, false>(Y0, Y1, Y2, Y3, lds, pk);  // Y*T
    z4(Z0, Z1, Z2, Z3);
    mm64<PP4, PP2, false, false>(Z0, Z1, Z2, Z3, lds, pk);  // T*Z
    wrhi64<PP3, false, false>(lds, wo, ev, jd, Y0, Y1, Y2, Y3, dmask, 0.f, 0.f);
    wrhi64<PP2, false, false>(lds, wo, ev, jd, Z0, Z1, Z2, Z3, dmask, 0.f, 0.f);
  }

  // L1 restore: Y = X'(split P0/P1) * Zh(P2) -> split P3/P4
  z4(Y0, Y1, Y2, Y3);
  mm64<PP0, PP2, true, false>(Y0, Y1, Y2, Y3, lds, pk);
  wrsp64<PP3>(lds, wo, ev, pl, jd, Y0, Y1, Y2, Y3);
  // L1 delta (Y only): D = 0.5(I - Zh*Ysplit) -> P0 hi
  pre4(A0, A1, A2, A3, dmask, -1.f);
  mm64<PP2, PP3, false, true>(A0, A1, A2, A3, lds, pk);
  wrhi64<PP0, true, false>(lds, wo, ev, jd, A0, A1, A2, A3, dmask, -0.5f, 0.f);
  // Y += Yh(P3)*D(P0);  X2' = Y -> split P3/P4;  T0 = 1.5I-0.5Y -> P2
  mm64<PP3, PP0, false, false>(Y0, Y1, Y2, Y3, lds, pk);
  wrsp64<PP3>(lds, wo, ev, pl, jd, Y0, Y1, Y2, Y3);
  wrhi64<PP2, true, true>(lds, wo, ev, jd, Y0, Y1, Y2, Y3, dmask, -0.5f, 1.5f);

  // L2 it1: Y = X2'h(P3) * T0(P2) -> P0 hi
  z4(A0, A1, A2, A3);
  mm64<PP3, PP2, false, false>(A0, A1, A2, A3, lds, pk);
  wrhi64<PP0, false, false>(lds, wo, ev, jd, A0, A1, A2, A3, dmask, 0.f, 0.f);

  // L2 bf16 iters 2..3: Y=P0, Z=P2, T=P1
#pragma unroll 1
  for (int it = 0; it < 2; ++it) {
    pre4(A0, A1, A2, A3, dmask, -3.f);
    mm64<PP2, PP0, false, false>(A0, A1, A2, A3, lds, pk);
    wrhi64<PP1, true, false>(lds, wo, ev, jd, A0, A1, A2, A3, dmask, -0.5f, 0.f);
    z4(Y0, Y1, Y2, Y3);
    mm64<PP0, PP1, false, false>(Y0, Y1, Y2, Y3, lds, pk);
    z4(Z0, Z1, Z2, Z3);
    mm64<PP1, PP2, false, false>(Z0, Z1, Z2, Z3, lds, pk);
    wrhi64<PP0, false, false>(lds, wo, ev, jd, Y0, Y1, Y2, Y3, dmask, 0.f, 0.f);
    wrhi64<PP2, false, false>(lds, wo, ev, jd, Z0, Z1, Z2, Z3, dmask, 0.f, 0.f);
  }

  // L2 restore: q16(Z); Y = X2'(split P3/P4) * Zh(P2) -> split P0/P1
  q16t(Z0); q16t(Z1); q16t(Z2); q16t(Z3);
  z4(Y0, Y1, Y2, Y3);
  mm64<PP3, PP2, true, false>(Y0, Y1, Y2, Y3, lds, pk);
  wrsp64<PP0>(lds, wo, ev, pl, jd, Y0, Y1, Y2, Y3);
  // L2 delta4: D = 0.5(I - Zh*Ysplit) -> P3 hi (X2' dead)
  pre4(A0, A1, A2, A3, dmask, -1.f);
  mm64<PP2, PP0, false, true>(A0, A1, A2, A3, lds, pk);
  wrhi64<PP3, true, false>(lds, wo, ev, jd, A0, A1, A2, A3, dmask, -0.5f, 0.f);
  mm64<PP0, PP3, false, false>(Y0, Y1, Y2, Y3, lds, pk);  // Y += Yh*D
  mm64<PP3, PP2, false, false>(Z0, Z1, Z2, Z3, lds, pk);  // Z += D*Zh
  wrsp64<PP0>(lds, wo, ev, pl, jd, Y0, Y1, Y2, Y3);
  q16t(Z0); q16t(Z1); q16t(Z2); q16t(Z3);
  wrhi64<PP2, false, false>(lds, wo, ev, jd, Z0, Z1, Z2, Z3, dmask, 0.f, 0.f);
  // L2 delta5 (masters final)
  pre4(A0, A1, A2, A3, dmask, -1.f);
  mm64<PP2, PP0, false, true>(A0, A1, A2, A3, lds, pk);
  wrhi64<PP3, true, false>(lds, wo, ev, jd, A0, A1, A2, A3, dmask, -0.5f, 0.f);
  mm64<PP0, PP3, false, false>(Y0, Y1, Y2, Y3, lds, pk);
  mm64<PP3, PP2, false, false>(Z0, Z1, Z2, Z3, lds, pk);

  // S = ca*Y - cb*Z -> split P0/P1
  {
    const float ca = 0.80141224f;  // 6.6^{1/4}/2
    const float cb = 0.31194493f;  // 1/(2*6.6^{1/4})
#pragma unroll
    for (int r = 0; r < 16; ++r) {
      A0[r] = ca * Y0[r] - cb * Z0[r];
      A1[r] = ca * Y1[r] - cb * Z1[r];
      A2[r] = ca * Y2[r] - cb * Z2[r];
      A3[r] = ca * Y3[r] - cb * Z3[r];
    }
  }
  wrsp64<PP0>(lds, wo, ev, pl, jd, A0, A1, A2, A3);

  // S2 = S*S (drop lo*lo): S2h -> P2; q = A11*S2 + A9*I -> P3
  z4(Y0, Y1, Y2, Y3);
  mm64<PP0, PP0, true, true>(Y0, Y1, Y2, Y3, lds, pk);
  wrhi64<PP2, false, false>(lds, wo, ev, jd, Y0, Y1, Y2, Y3, dmask, 0.f, 0.f);
  wrhi64<PP3, true, true>(lds, wo, ev, jd, Y0, Y1, Y2, Y3, dmask, -0.08948864f,
                          0.12152778f);

  // asinh Horner (bf16): 3 steps, q(P3) * S2(P2) + c*I -> P3
  {
    const float acoef[3] = {-0.17857143f, 0.3f, -0.66666667f};
#pragma unroll 1
    for (int j = 0; j < 3; ++j) {
      pre4(A0, A1, A2, A3, dmask, acoef[j]);
      mm64<PP3, PP2, false, false>(A0, A1, A2, A3, lds, pk);
      wrhi64<PP3, false, false>(lds, wo, ev, jd, A0, A1, A2, A3, dmask, 0.f, 0.f);
    }
  }
  // q4 = q*S2 + 4I -> split P3/P4
  pre4(A0, A1, A2, A3, dmask, 4.f);
  mm64<PP3, PP2, false, false>(A0, A1, A2, A3, lds, pk);
  wrsp64<PP3>(lds, wo, ev, pl, jd, A0, A1, A2, A3);

  // L = S(P0/P1) * q4(P3/P4), all 4 tiles in regs -> pool directly from regs
  z4(Y0, Y1, Y2, Y3);
  mm64<PP0, PP3, true, true>(Y0, Y1, Y2, Y3, lds, pk);
  // pool: P2m = P/2 split -> P0/P1; q2 = d8*P2m + d7*I split -> P2/P3
  {
    const float d8 = 2.4801587e-5f, d7 = 1.9841270e-4f;
#pragma unroll
    for (int t = 0; t < 4; ++t) {
      const f32x16& C = t == 0 ? Y0 : t == 1 ? Y1 : t == 2 ? Y2 : Y3;
      const int bi = (t >> 1) * 16, bj = (t & 1) * 16;
#pragma unroll
      for (int q = 0; q < 8; ++q) {
        float rp = C[2 * q] + C[2 * q + 1];      // row-pair sum (in-lane)
        float cs = rp + dppswap(rp);             // col-pair sum (lane^1)
        float p = 0.125f * cs;
        const int row = bi + (q & 1) + 4 * (q >> 1) + 2 * half;
        const int col = bj + (ln31 >> 1);
        float qv = d8 * p + ((row == col) ? d7 : 0.f);
        unsigned phw = cvtpk(p, p);
        float plo = p - __uint_as_float(phw << 16);
        unsigned plw = cvtpk(plo, plo);
        unsigned qhw = cvtpk(qv, qv);
        float qlo = qv - __uint_as_float(qhw << 16);
        unsigned qlw = cvtpk(qlo, qlo);
        const int off = row * 128 + (((col >> 3) ^ (row & 7)) << 4) + (col & 7) * 2;
        if (ev) {
          *(short*)(lds + PP0 + off) = (short)phw;
          *(short*)(lds + PP1 + off) = (short)plw;
          *(short*)(lds + PP2 + off) = (short)qhw;
          *(short*)(lds + PP3 + off) = (short)qlw;
        }
      }
    }
  }

  // exp(P/2) Horner: 7 in-place steps, q2(P2/P3) * x(P0/P1) + c*I -> P2/P3
  {
    const float dcoef[7] = {1.f / 720.f, 1.f / 120.f, 1.f / 24.f,
                            1.f / 6.f,   0.5f,        1.f,       1.f};
#pragma unroll 1
    for (int j = 0; j < 7; ++j) {
      f32x16 acc;
#pragma unroll
      for (int r = 0; r < 16; ++r) acc[r] = dcoef[j] * dmask[r];
      mm32<PP2, PP0>(acc, lds, pk);
      wrsp32<PP2>(lds, wo, ev, pl, acc);
    }
  }

  // OUT = H*H -> global fp32
  {
    f32x16 acc;
#pragma unroll
    for (int r = 0; r < 16; ++r) acc[r] = 0.f;
    mm32<PP2, PP2>(acc, lds, pk);
    float* og = out + (size_t)blockIdx.x * 1024;
#pragma unroll
    for (int r = 0; r < 16; ++r)
      og[((r & 3) + 8 * (r >> 2) + 4 * half) * 32 + ln31] = acc[r];
  }
}

extern "C" void kernel_launch(void* const* d_in, const int* in_sizes, int n_in,
                              void* d_out, int out_size, void* d_ws, size_t ws_size,
                              hipStream_t stream) {
  const float* X = (const float*)d_in[0];
  float* out = (float*)d_out;
  const int batch = in_sizes[0] / 4096;  // 8192
  spd_pool_kernel<<<batch, 64, 0, stream>>>(X, out);
}

// Round 4
// 491.648 us; speedup vs baseline: 1.3920x; 1.3920x over previous
//
#include <hip/hip_runtime.h>

typedef __attribute__((ext_vector_type(8))) short short8;
typedef __attribute__((ext_vector_type(16))) float f32x16;

// 5 planes of 8192 B (64 rows x 128 B). Split pairs = adjacent planes
// (lo = hi + 8192). Same-bank hi/lo pairing is only ever 2-way = free.
#define PL 8192
#define PP0 0
#define PP1 8192
#define PP2 16384
#define PP3 24576
#define PP4 32768

__device__ __forceinline__ int swadr(int m, int kc) {
  return m * 128 + ((kc ^ (m & 7)) << 4);
}

// packed f32->bf16 RNE (no builtin on gfx950)
__device__ __forceinline__ unsigned int cvtpk(float a, float b) {
  unsigned int r;
  asm("v_cvt_pk_bf16_f32 %0, %1, %2" : "=v"(r) : "v"(a), "v"(b));
  return r;
}
__device__ __forceinline__ float dppswap(float v) {  // lane ^ 1
  return __int_as_float(
      __builtin_amdgcn_mov_dpp(__float_as_int(v), 0xB1, 0xF, 0xF, true));
}
__device__ __forceinline__ f32x16 zero16() {
  f32x16 z;
#pragma unroll
  for (int i = 0; i < 16; ++i) z[i] = 0.f;
  return z;
}
__device__ __forceinline__ void q16x16(f32x16& v) {  // regs -> bf16 values
#pragma unroll
  for (int r = 0; r < 16; r += 2) {
    unsigned w = cvtpk(v[r], v[r + 1]);
    v[r] = __uint_as_float(w << 16);
    v[r + 1] = __uint_as_float(w & 0xFFFF0000u);
  }
}

// ---- init stores (thread-indexed) ----
__device__ __forceinline__ void store_hi8(char* dst, const float* v) {
  *(uint4*)dst = make_uint4(cvtpk(v[0], v[1]), cvtpk(v[2], v[3]),
                            cvtpk(v[4], v[5]), cvtpk(v[6], v[7]));
}
__device__ __forceinline__ void split_store8(char* dst, const float* v) {
  unsigned h[4], l[4];
#pragma unroll
  for (int j = 0; j < 4; ++j) {
    unsigned hw = cvtpk(v[2 * j], v[2 * j + 1]);
    float h0 = __uint_as_float(hw << 16);
    float h1 = __uint_as_float(hw & 0xFFFF0000u);
    l[j] = cvtpk(v[2 * j] - h0, v[2 * j + 1] - h1);
    h[j] = hw;
  }
  *(uint4*)dst = make_uint4(h[0], h[1], h[2], h[3]);
  *(uint4*)(dst + PL) = make_uint4(l[0], l[1], l[2], l[3]);
}

// ---- MFMA macs: per-lane base ptrs, plane select by template immediate ----
template <int NK, int OA, int OB, int N>
__device__ __forceinline__ void mac1(f32x16& acc, char* const (&pA)[N],
                                     char* const (&pB)[N]) {
#pragma unroll
  for (int s = 0; s < NK; ++s) {
    short8 a = *(const short8*)(pA[s] + OA);
    short8 b = *(const short8*)(pB[s] + OB);
    acc = __builtin_amdgcn_mfma_f32_32x32x16_bf16(a, b, acc, 0, 0, 0);
  }
}
template <int NK, int OA, int OB, int N>  // A split, B bf16
__device__ __forceinline__ void mac2A(f32x16& acc, char* const (&pA)[N],
                                      char* const (&pB)[N]) {
#pragma unroll
  for (int s = 0; s < NK; ++s) {
    short8 ah = *(const short8*)(pA[s] + OA);
    short8 al = *(const short8*)(pA[s] + OA + PL);
    short8 b = *(const short8*)(pB[s] + OB);
    acc = __builtin_amdgcn_mfma_f32_32x32x16_bf16(ah, b, acc, 0, 0, 0);
    acc = __builtin_amdgcn_mfma_f32_32x32x16_bf16(al, b, acc, 0, 0, 0);
  }
}
template <int NK, int OA, int OB, int N>  // A bf16, B split
__device__ __forceinline__ void mac2B(f32x16& acc, char* const (&pA)[N],
                                      char* const (&pB)[N]) {
#pragma unroll
  for (int s = 0; s < NK; ++s) {
    short8 a = *(const short8*)(pA[s] + OA);
    short8 bh = *(const short8*)(pB[s] + OB);
    short8 bl = *(const short8*)(pB[s] + OB + PL);
    acc = __builtin_amdgcn_mfma_f32_32x32x16_bf16(a, bh, acc, 0, 0, 0);
    acc = __builtin_amdgcn_mfma_f32_32x32x16_bf16(a, bl, acc, 0, 0, 0);
  }
}
template <int NK, int OA, int OB, int N>  // both split (drop lo*lo)
__device__ __forceinline__ void mac3(f32x16& acc, char* const (&pA)[N],
                                     char* const (&pB)[N]) {
#pragma unroll
  for (int s = 0; s < NK; ++s) {
    short8 ah = *(const short8*)(pA[s] + OA);
    short8 al = *(const short8*)(pA[s] + OA + PL);
    short8 bh = *(const short8*)(pB[s] + OB);
    short8 bl = *(const short8*)(pB[s] + OB + PL);
    acc = __builtin_amdgcn_mfma_f32_32x32x16_bf16(ah, bh, acc, 0, 0, 0);
    acc = __builtin_amdgcn_mfma_f32_32x32x16_bf16(ah, bl, acc, 0, 0, 0);
    acc = __builtin_amdgcn_mfma_f32_32x32x16_bf16(al, bh, acc, 0, 0, 0);
  }
}

// ---- C-tile writes: precomputed word offsets, DPP + cvt_pk packing ----
template <int OFF>
__device__ __forceinline__ void write_hi(char* lds, const int (&wo)[16], bool ev,
                                         const f32x16& vals) {
#pragma unroll
  for (int r = 0; r < 16; ++r) {
    float vn = dppswap(vals[r]);
    unsigned hw = cvtpk(vals[r], vn);
    if (ev) *(unsigned*)(lds + OFF + wo[r]) = hw;
  }
}
template <int OFF>
__device__ __forceinline__ void write_split(char* lds, const int (&wo)[16],
                                            bool ev, int pl, const f32x16& vals,
                                            int r0, int r1) {
#pragma unroll
  for (int r = 0; r < 16; ++r) {
    if (r < r0 || r >= r1) continue;
    float v = vals[r];
    float vn = dppswap(v);
    unsigned hw = cvtpk(v, vn);
    float lo = v - __uint_as_float(hw << 16);
    float lon = dppswap(lo);
    unsigned lw = cvtpk(lon, lo);
    *(unsigned*)(lds + OFF + pl + wo[r]) = ev ? hw : lw;
  }
}

__global__ void __launch_bounds__(256, 4)
spd_pool_kernel(const float* __restrict__ X, float* __restrict__ out) {
  __shared__ __align__(16) char lds[5 * 8192];  // 40960 B -> 4 blocks/CU

  const int tid = threadIdx.x;
  const int lane = tid & 63;
  const int wv = tid >> 6;
  const int R = (wv >> 1) * 32;
  const int Cc = (wv & 1) * 32;
  const int half = lane >> 5;
  const int ln31 = lane & 31;
  const bool ev = (ln31 & 1) == 0;
  const int pl = ev ? 0 : PL;

  // per-lane ds read base pointers; plane chosen by template imm
  char* pA[4];
  char* pB[4];
#pragma unroll
  for (int s = 0; s < 4; ++s) {
    const int kc = 2 * s + half;
    pA[s] = lds + swadr(R + ln31, kc);
    pB[s] = lds + swadr(Cc + ln31, kc);
  }
  // per-lane C-write word offsets (anchored at (R, Cc))
  int wo[16];
  {
    const int col0 = Cc + (ln31 & ~1);
    const int cchunk = col0 >> 3, cbyte = (col0 & 7) * 2;
    const int rbase = R + 4 * half;
#pragma unroll
    for (int r = 0; r < 16; ++r) {
      const int m = rbase + (r & 3) + 8 * (r >> 2);
      wo[r] = m * 128 + ((cchunk ^ (m & 7)) << 4) + cbyte;
    }
  }
  // diagonal mask of this thread's C fragment
  f32x16 dmask;
#pragma unroll
  for (int r = 0; r < 16; ++r)
    dmask[r] = (R + (r & 3) + 8 * (r >> 2) + 4 * half == Cc + ln31) ? 1.f : 0.f;

  f32x16 mY, mZ;

  // ======= init: P0/P1 = X' = X/6.6 (split); P2 = T0 =======
  {
    const int em = tid >> 2;
    const int ekc = (tid & 3) * 2;
    const int ec0 = ekc * 8;
    const float ic1 = 1.0f / 6.6f;
    const float* Xg = X + (size_t)blockIdx.x * 4096 + em * 64 + ec0;
    const float4* xp = (const float4*)Xg;
    float4 a = xp[0], b = xp[1], c = xp[2], d = xp[3];
    float v[16] = {a.x * ic1, a.y * ic1, a.z * ic1, a.w * ic1,
                   b.x * ic1, b.y * ic1, b.z * ic1, b.w * ic1,
                   c.x * ic1, c.y * ic1, c.z * ic1, c.w * ic1,
                   d.x * ic1, d.y * ic1, d.z * ic1, d.w * ic1};
    float t[16];
#pragma unroll
    for (int i = 0; i < 16; ++i)
      t[i] = ((em == ec0 + i) ? 1.5f : 0.f) - 0.5f * v[i];
    split_store8(lds + PP0 + swadr(em, ekc), v);
    split_store8(lds + PP0 + swadr(em, ekc + 1), v + 8);
    store_hi8(lds + PP2 + swadr(em, ekc), t);
    store_hi8(lds + PP2 + swadr(em, ekc + 1), t + 8);
  }
  __syncthreads();
  // L1 it1: Y = X'h(P0) * T0(P2) -> P3 hi
  mY = zero16();
  mac1<4, PP0, PP2>(mY, pA, pB);
  write_hi<PP3>(lds, wo, ev, mY);
  __syncthreads();
  // L1 bf16 iters 2..5: Z=P2, Y=P3, T=P4
#pragma unroll 1
  for (int it = 0; it < 4; ++it) {
    f32x16 a;
#pragma unroll
    for (int r = 0; r < 16; ++r) a[r] = -3.f * dmask[r];
    mac1<4, PP2, PP3>(a, pA, pB);
    f32x16 tv;
#pragma unroll
    for (int r = 0; r < 16; ++r) tv[r] = -0.5f * a[r];
    write_hi<PP4>(lds, wo, ev, tv);
    __syncthreads();
    mY = zero16();
    mac1<4, PP3, PP4>(mY, pA, pB);
    mZ = zero16();
    mac1<4, PP4, PP2>(mZ, pA, pB);
    __syncthreads();
    write_hi<PP3>(lds, wo, ev, mY);
    write_hi<PP2>(lds, wo, ev, mZ);
    __syncthreads();
  }
  // L1 restore: mY = X'(split P0/P1) * Zh(P2) -> split P3/P4
  mY = zero16();
  mac2A<4, PP0, PP2>(mY, pA, pB);
  write_split<PP3>(lds, wo, ev, pl, mY, 0, 16);
  __syncthreads();
  // L1 delta (Y only): D = 0.5(I - Zh*Ysplit) -> P0 hi (X' dead)
  {
    f32x16 a;
#pragma unroll
    for (int r = 0; r < 16; ++r) a[r] = -dmask[r];
    mac2B<4, PP2, PP3>(a, pA, pB);
    f32x16 dv;
#pragma unroll
    for (int r = 0; r < 16; ++r) dv[r] = -0.5f * a[r];
    write_hi<PP0>(lds, wo, ev, dv);
  }
  __syncthreads();
  mac1<4, PP3, PP0>(mY, pA, pB);  // mY += Yh*D
  __syncthreads();
  write_split<PP3>(lds, wo, ev, pl, mY, 0, 16);  // X2' -> P3/P4
  {
    f32x16 t0v;
#pragma unroll
    for (int r = 0; r < 16; ++r) t0v[r] = 1.5f * dmask[r] - 0.5f * mY[r];
    write_hi<PP2>(lds, wo, ev, t0v);  // T0 -> P2
  }
  __syncthreads();
  // L2 it1: Y = X2'h(P3) * T0(P2) -> P0 hi
  mY = zero16();
  mac1<4, PP3, PP2>(mY, pA, pB);
  write_hi<PP0>(lds, wo, ev, mY);
  __syncthreads();
  // L2 bf16 iters 2..3: Y=P0, Z=P2, T=P1
#pragma unroll 1
  for (int it = 0; it < 2; ++it) {
    f32x16 a;
#pragma unroll
    for (int r = 0; r < 16; ++r) a[r] = -3.f * dmask[r];
    mac1<4, PP2, PP0>(a, pA, pB);
    f32x16 tv;
#pragma unroll
    for (int r = 0; r < 16; ++r) tv[r] = -0.5f * a[r];
    write_hi<PP1>(lds, wo, ev, tv);
    __syncthreads();
    mY = zero16();
    mac1<4, PP0, PP1>(mY, pA, pB);
    mZ = zero16();
    mac1<4, PP1, PP2>(mZ, pA, pB);
    __syncthreads();
    write_hi<PP0>(lds, wo, ev, mY);
    write_hi<PP2>(lds, wo, ev, mZ);
    __syncthreads();
  }
  // L2 restore: q16(Z); Y = X2'(P3/P4) * Zh(P2) -> split P0/P1
  q16x16(mZ);
  mY = zero16();
  mac2A<4, PP3, PP2>(mY, pA, pB);
  write_split<PP0>(lds, wo, ev, pl, mY, 0, 16);
  __syncthreads();
  // L2 delta4: D = 0.5(I - Zh*Ysplit) -> P3 hi (X2' dead)
  {
    f32x16 a;
#pragma unroll
    for (int r = 0; r < 16; ++r) a[r] = -dmask[r];
    mac2B<4, PP2, PP0>(a, pA, pB);
    f32x16 dv;
#pragma unroll
    for (int r = 0; r < 16; ++r) dv[r] = -0.5f * a[r];
    write_hi<PP3>(lds, wo, ev, dv);
  }
  __syncthreads();
  mac1<4, PP0, PP3>(mY, pA, pB);  // mY += Yh*D
  mac1<4, PP3, PP2>(mZ, pA, pB);  // mZ += D*Zh
  __syncthreads();
  write_split<PP0>(lds, wo, ev, pl, mY, 0, 16);
  q16x16(mZ);
  write_hi<PP2>(lds, wo, ev, mZ);
  __syncthreads();
  // L2 delta5 (masters final, no writeback)
  {
    f32x16 a;
#pragma unroll
    for (int r = 0; r < 16; ++r) a[r] = -dmask[r];
    mac2B<4, PP2, PP0>(a, pA, pB);
    f32x16 dv;
#pragma unroll
    for (int r = 0; r < 16; ++r) dv[r] = -0.5f * a[r];
    write_hi<PP3>(lds, wo, ev, dv);
  }
  __syncthreads();
  mac1<4, PP0, PP3>(mY, pA, pB);
  mac1<4, PP3, PP2>(mZ, pA, pB);
  // S = ca*Y - cb*Z -> split P0/P1
  f32x16 sv;
  {
    const float ca = 0.80141224f;  // 6.6^{1/4}/2
    const float cb = 0.31194493f;  // 1/(2*6.6^{1/4})
#pragma unroll
    for (int r = 0; r < 16; ++r) sv[r] = ca * mY[r] - cb * mZ[r];
  }
  __syncthreads();
  write_split<PP0>(lds, wo, ev, pl, sv, 0, 16);
  __syncthreads();
  // S2 = S*S (drop ll): S2h -> P2; q = A11*S2 + A9*I -> P3
  {
    f32x16 s2 = zero16();
    mac3<4, PP0, PP0>(s2, pA, pB);
    const float A11 = -0.08948864f, A9 = 0.12152778f;
    f32x16 qv;
#pragma unroll
    for (int r = 0; r < 16; ++r) qv[r] = A11 * s2[r] + A9 * dmask[r];
    write_hi<PP2>(lds, wo, ev, s2);
    write_hi<PP3>(lds, wo, ev, qv);
  }
  __syncthreads();
  // asinh Horner (bf16): 3 steps, q(P3)*S2(P2) + c*I -> P3
  {
    const float acoef[3] = {-0.17857143f, 0.3f, -0.66666667f};
#pragma unroll 1
    for (int j = 0; j < 3; ++j) {
      f32x16 a;
#pragma unroll
      for (int r = 0; r < 16; ++r) a[r] = acoef[j] * dmask[r];
      mac1<4, PP3, PP2>(a, pA, pB);
      __syncthreads();
      write_hi<PP3>(lds, wo, ev, a);
      __syncthreads();
    }
  }
  // q4 = q*S2 + 4I -> split P3/P4
  {
    f32x16 a;
#pragma unroll
    for (int r = 0; r < 16; ++r) a[r] = 4.f * dmask[r];
    mac1<4, PP3, PP2>(a, pA, pB);
    __syncthreads();
    write_split<PP3>(lds, wo, ev, pl, a, 0, 16);
    __syncthreads();
  }
  // L = S(P0/P1) * q4(P3/P4); pool DIRECTLY from regs
  {
    f32x16 mL = zero16();
    mac3<4, PP0, PP3>(mL, pA, pB);
    __syncthreads();  // all reads of P0..P4 done; safe to overwrite
    const float d8 = 2.4801587e-5f, d7 = 1.9841270e-4f;
#pragma unroll
    for (int q = 0; q < 8; ++q) {
      float rp = mL[2 * q] + mL[2 * q + 1];  // row-pair (in-lane)
      float cs = rp + dppswap(rp);           // col-pair (lane^1)
      float p = 0.125f * cs;
      const int row = R / 2 + (q & 1) + 4 * (q >> 1) + 2 * half;
      const int col = Cc / 2 + (ln31 >> 1);
      float qv = d8 * p + ((row == col) ? d7 : 0.f);
      unsigned phw = cvtpk(p, p);
      float plo = p - __uint_as_float(phw << 16);
      unsigned plw = cvtpk(plo, plo);
      unsigned qhw = cvtpk(qv, qv);
      float qlo = qv - __uint_as_float(qhw << 16);
      unsigned qlw = cvtpk(qlo, qlo);
      const int off = row * 128 + (((col >> 3) ^ (row & 7)) << 4) + (col & 7) * 2;
      if (ev) {
        *(short*)(lds + PP0 + off) = (short)phw;  // P2m hi
        *(short*)(lds + PP1 + off) = (short)plw;  // P2m lo
        *(short*)(lds + PP2 + off) = (short)qhw;  // q2 hi
        *(short*)(lds + PP3 + off) = (short)qlw;  // q2 lo
      }
    }
  }
  __syncthreads();
  // exp-phase per-lane setup (32x32 role)
  char* pE[2];
#pragma unroll
  for (int s = 0; s < 2; ++s) pE[s] = lds + swadr(ln31, 2 * s + half);
  f32x16 dmask2;
#pragma unroll
  for (int r = 0; r < 16; ++r)
    dmask2[r] = ((r & 3) + 8 * (r >> 2) + 4 * half == ln31) ? 1.f : 0.f;
  int wo2[16];
  {
    const int col0 = ln31 & ~1;
    const int cchunk = col0 >> 3, cbyte = (col0 & 7) * 2;
    const int rbase = 4 * half;
#pragma unroll
    for (int r = 0; r < 16; ++r) {
      const int m = rbase + (r & 3) + 8 * (r >> 2);
      wo2[r] = m * 128 + ((cchunk ^ (m & 7)) << 4) + cbyte;
    }
  }
  // exp(P/2) Horner: 7 steps, q2(P2/P3)*x(P0/P1) + c*I -> P2/P3 (dup compute,
  // each wave writes its row-slice)
  {
    const float dcoef[7] = {1.f / 720.f, 1.f / 120.f, 1.f / 24.f,
                            1.f / 6.f,   0.5f,        1.f,       1.f};
#pragma unroll 1
    for (int j = 0; j < 7; ++j) {
      f32x16 acc;
#pragma unroll
      for (int r = 0; r < 16; ++r) acc[r] = dcoef[j] * dmask2[r];
      mac3<2, PP2, PP0>(acc, pE, pE);
      __syncthreads();
      write_split<PP2>(lds, wo2, ev, pl, acc, 4 * wv, 4 * wv + 4);
      __syncthreads();
    }
  }
  // OUT = H*H -> global fp32
  {
    f32x16 acc = zero16();
    mac3<2, PP2, PP2>(acc, pE, pE);
    float* og = out + (size_t)blockIdx.x * 1024;
#pragma unroll
    for (int r = 0; r < 16; ++r) {
      if (r < 4 * wv || r >= 4 * wv + 4) continue;
      int rl = (r & 3) + 8 * (r >> 2) + 4 * half;
      og[rl * 32 + ln31] = acc[r];
    }
  }
}

extern "C" void kernel_launch(void* const* d_in, const int* in_sizes, int n_in,
                              void* d_out, int out_size, void* d_ws, size_t ws_size,
                              hipStream_t stream) {
  const float* X = (const float*)d_in[0];
  float* out = (float*)d_out;
  const int batch = in_sizes[0] / 4096;  // 8192
  spd_pool_kernel<<<batch, 256, 0, stream>>>(X, out);
}

// Round 6
// 481.175 us; speedup vs baseline: 1.4223x; 1.0218x over previous
//
#include <hip/hip_runtime.h>

typedef __attribute__((ext_vector_type(8))) short short8;
typedef __attribute__((ext_vector_type(16))) float f32x16;

// 5 planes of 8192 B (64 rows x 128 B). Split pairs = adjacent planes
// (lo = hi + 8192). Same-bank hi/lo pairing is only ever 2-way = free.
#define PL 8192
#define PP0 0
#define PP1 8192
#define PP2 16384
#define PP3 24576
#define PP4 32768

__device__ __forceinline__ int swadr(int m, int kc) {
  return m * 128 + ((kc ^ (m & 7)) << 4);
}

// packed f32->bf16 RNE (no builtin on gfx950)
__device__ __forceinline__ unsigned int cvtpk(float a, float b) {
  unsigned int r;
  asm("v_cvt_pk_bf16_f32 %0, %1, %2" : "=v"(r) : "v"(a), "v"(b));
  return r;
}
__device__ __forceinline__ float dppswap(float v) {  // lane ^ 1
  return __int_as_float(
      __builtin_amdgcn_mov_dpp(__float_as_int(v), 0xB1, 0xF, 0xF, true));
}
__device__ __forceinline__ f32x16 zero16() {
  f32x16 z;
#pragma unroll
  for (int i = 0; i < 16; ++i) z[i] = 0.f;
  return z;
}
__device__ __forceinline__ void q16x16(f32x16& v) {  // regs -> bf16 values
#pragma unroll
  for (int r = 0; r < 16; r += 2) {
    unsigned w = cvtpk(v[r], v[r + 1]);
    v[r] = __uint_as_float(w << 16);
    v[r + 1] = __uint_as_float(w & 0xFFFF0000u);
  }
}

// ---- init stores (thread-indexed) ----
__device__ __forceinline__ void store_hi8(char* dst, const float* v) {
  *(uint4*)dst = make_uint4(cvtpk(v[0], v[1]), cvtpk(v[2], v[3]),
                            cvtpk(v[4], v[5]), cvtpk(v[6], v[7]));
}
__device__ __forceinline__ void split_store8(char* dst, const float* v) {
  unsigned h[4], l[4];
#pragma unroll
  for (int j = 0; j < 4; ++j) {
    unsigned hw = cvtpk(v[2 * j], v[2 * j + 1]);
    float h0 = __uint_as_float(hw << 16);
    float h1 = __uint_as_float(hw & 0xFFFF0000u);
    l[j] = cvtpk(v[2 * j] - h0, v[2 * j + 1] - h1);
    h[j] = hw;
  }
  *(uint4*)dst = make_uint4(h[0], h[1], h[2], h[3]);
  *(uint4*)(dst + PL) = make_uint4(l[0], l[1], l[2], l[3]);
}

// ---- MFMA macs: per-lane base ptrs, plane select by template immediate ----
template <int NK, int OA, int OB, int N>
__device__ __forceinline__ void mac1(f32x16& acc, char* const (&pA)[N],
                                     char* const (&pB)[N]) {
#pragma unroll
  for (int s = 0; s < NK; ++s) {
    short8 a = *(const short8*)(pA[s] + OA);
    short8 b = *(const short8*)(pB[s] + OB);
    acc = __builtin_amdgcn_mfma_f32_32x32x16_bf16(a, b, acc, 0, 0, 0);
  }
}
template <int NK, int OA, int OB, int N>  // A split, B bf16
__device__ __forceinline__ void mac2A(f32x16& acc, char* const (&pA)[N],
                                      char* const (&pB)[N]) {
#pragma unroll
  for (int s = 0; s < NK; ++s) {
    short8 ah = *(const short8*)(pA[s] + OA);
    short8 al = *(const short8*)(pA[s] + OA + PL);
    short8 b = *(const short8*)(pB[s] + OB);
    acc = __builtin_amdgcn_mfma_f32_32x32x16_bf16(ah, b, acc, 0, 0, 0);
    acc = __builtin_amdgcn_mfma_f32_32x32x16_bf16(al, b, acc, 0, 0, 0);
  }
}
template <int NK, int OA, int OB, int N>  // A bf16, B split
__device__ __forceinline__ void mac2B(f32x16& acc, char* const (&pA)[N],
                                      char* const (&pB)[N]) {
#pragma unroll
  for (int s = 0; s < NK; ++s) {
    short8 a = *(const short8*)(pA[s] + OA);
    short8 bh = *(const short8*)(pB[s] + OB);
    short8 bl = *(const short8*)(pB[s] + OB + PL);
    acc = __builtin_amdgcn_mfma_f32_32x32x16_bf16(a, bh, acc, 0, 0, 0);
    acc = __builtin_amdgcn_mfma_f32_32x32x16_bf16(a, bl, acc, 0, 0, 0);
  }
}
template <int NK, int OA, int OB, int N>  // both split (drop lo*lo)
__device__ __forceinline__ void mac3(f32x16& acc, char* const (&pA)[N],
                                     char* const (&pB)[N]) {
#pragma unroll
  for (int s = 0; s < NK; ++s) {
    short8 ah = *(const short8*)(pA[s] + OA);
    short8 al = *(const short8*)(pA[s] + OA + PL);
    short8 bh = *(const short8*)(pB[s] + OB);
    short8 bl = *(const short8*)(pB[s] + OB + PL);
    acc = __builtin_amdgcn_mfma_f32_32x32x16_bf16(ah, bh, acc, 0, 0, 0);
    acc = __builtin_amdgcn_mfma_f32_32x32x16_bf16(ah, bl, acc, 0, 0, 0);
    acc = __builtin_amdgcn_mfma_f32_32x32x16_bf16(al, bh, acc, 0, 0, 0);
  }
}

// ---- C-tile writes: precomputed word offsets, DPP + cvt_pk packing ----
template <int OFF>
__device__ __forceinline__ void write_hi(char* lds, const int (&wo)[16], bool ev,
                                         const f32x16& vals) {
#pragma unroll
  for (int r = 0; r < 16; ++r) {
    float vn = dppswap(vals[r]);
    unsigned hw = cvtpk(vals[r], vn);
    if (ev) *(unsigned*)(lds + OFF + wo[r]) = hw;
  }
}
template <int OFF>
__device__ __forceinline__ void write_split(char* lds, const int (&wo)[16],
                                            bool ev, int pl, const f32x16& vals,
                                            int r0, int r1) {
#pragma unroll
  for (int r = 0; r < 16; ++r) {
    if (r < r0 || r >= r1) continue;
    float v = vals[r];
    float vn = dppswap(v);
    unsigned hw = cvtpk(v, vn);
    float lo = v - __uint_as_float(hw << 16);
    float lon = dppswap(lo);
    unsigned lw = cvtpk(lon, lo);
    *(unsigned*)(lds + OFF + pl + wo[r]) = ev ? hw : lw;
  }
}

__global__ void __launch_bounds__(256, 4)
spd_pool_kernel(const float* __restrict__ X, float* __restrict__ out) {
  __shared__ __align__(16) char lds[5 * 8192];  // 40960 B -> 4 blocks/CU

  const int tid = threadIdx.x;
  const int lane = tid & 63;
  const int wv = tid >> 6;
  const int R = (wv >> 1) * 32;
  const int Cc = (wv & 1) * 32;
  const int half = lane >> 5;
  const int ln31 = lane & 31;
  const bool ev = (ln31 & 1) == 0;
  const int pl = ev ? 0 : PL;

  // per-lane ds read base pointers; plane chosen by template imm
  char* pA[4];
  char* pB[4];
#pragma unroll
  for (int s = 0; s < 4; ++s) {
    const int kc = 2 * s + half;
    pA[s] = lds + swadr(R + ln31, kc);
    pB[s] = lds + swadr(Cc + ln31, kc);
  }
  // per-lane C-write word offsets (anchored at (R, Cc))
  int wo[16];
  {
    const int col0 = Cc + (ln31 & ~1);
    const int cchunk = col0 >> 3, cbyte = (col0 & 7) * 2;
    const int rbase = R + 4 * half;
#pragma unroll
    for (int r = 0; r < 16; ++r) {
      const int m = rbase + (r & 3) + 8 * (r >> 2);
      wo[r] = m * 128 + ((cchunk ^ (m & 7)) << 4) + cbyte;
    }
  }
  // diagonal mask of this thread's C fragment
  f32x16 dmask;
#pragma unroll
  for (int r = 0; r < 16; ++r)
    dmask[r] = (R + (r & 3) + 8 * (r >> 2) + 4 * half == Cc + ln31) ? 1.f : 0.f;

  f32x16 mY, mZ;

  // ======= init: P0/P1 = X' = X/6.6 (split); P2 = T0 =======
  {
    const int em = tid >> 2;
    const int ekc = (tid & 3) * 2;
    const int ec0 = ekc * 8;
    const float ic1 = 1.0f / 6.6f;
    const float* Xg = X + (size_t)blockIdx.x * 4096 + em * 64 + ec0;
    const float4* xp = (const float4*)Xg;
    float4 a = xp[0], b = xp[1], c = xp[2], d = xp[3];
    float v[16] = {a.x * ic1, a.y * ic1, a.z * ic1, a.w * ic1,
                   b.x * ic1, b.y * ic1, b.z * ic1, b.w * ic1,
                   c.x * ic1, c.y * ic1, c.z * ic1, c.w * ic1,
                   d.x * ic1, d.y * ic1, d.z * ic1, d.w * ic1};
    float t[16];
#pragma unroll
    for (int i = 0; i < 16; ++i)
      t[i] = ((em == ec0 + i) ? 1.5f : 0.f) - 0.5f * v[i];
    split_store8(lds + PP0 + swadr(em, ekc), v);
    split_store8(lds + PP0 + swadr(em, ekc + 1), v + 8);
    store_hi8(lds + PP2 + swadr(em, ekc), t);
    store_hi8(lds + PP2 + swadr(em, ekc + 1), t + 8);
  }
  __syncthreads();
  // L1 it1: Y = X'h(P0) * T0(P2) -> P3 hi
  mY = zero16();
  mac1<4, PP0, PP2>(mY, pA, pB);
  write_hi<PP3>(lds, wo, ev, mY);
  __syncthreads();
  // L1 bf16 iters 2..5: Z=P2, Y=P3, T=P4
#pragma unroll 1
  for (int it = 0; it < 4; ++it) {
    f32x16 a;
#pragma unroll
    for (int r = 0; r < 16; ++r) a[r] = -3.f * dmask[r];
    mac1<4, PP2, PP3>(a, pA, pB);
    f32x16 tv;
#pragma unroll
    for (int r = 0; r < 16; ++r) tv[r] = -0.5f * a[r];
    write_hi<PP4>(lds, wo, ev, tv);
    __syncthreads();
    mY = zero16();
    mac1<4, PP3, PP4>(mY, pA, pB);
    mZ = zero16();
    mac1<4, PP4, PP2>(mZ, pA, pB);
    __syncthreads();
    write_hi<PP3>(lds, wo, ev, mY);
    write_hi<PP2>(lds, wo, ev, mZ);
    __syncthreads();
  }
  // L1 restore: mY = X'(split P0/P1) * Zh(P2) -> split P3/P4
  mY = zero16();
  mac2A<4, PP0, PP2>(mY, pA, pB);
  write_split<PP3>(lds, wo, ev, pl, mY, 0, 16);
  __syncthreads();
  // L1 delta (Y only): D = 0.5(I - Zh*Ysplit) -> P0 hi (X' dead)
  {
    f32x16 a;
#pragma unroll
    for (int r = 0; r < 16; ++r) a[r] = -dmask[r];
    mac2B<4, PP2, PP3>(a, pA, pB);
    f32x16 dv;
#pragma unroll
    for (int r = 0; r < 16; ++r) dv[r] = -0.5f * a[r];
    write_hi<PP0>(lds, wo, ev, dv);
  }
  __syncthreads();
  mac1<4, PP3, PP0>(mY, pA, pB);  // mY += Yh*D
  __syncthreads();
  write_split<PP3>(lds, wo, ev, pl, mY, 0, 16);  // X2' -> P3/P4
  {
    f32x16 t0v;
#pragma unroll
    for (int r = 0; r < 16; ++r) t0v[r] = 1.5f * dmask[r] - 0.5f * mY[r];
    write_hi<PP2>(lds, wo, ev, t0v);  // T0 -> P2
  }
  __syncthreads();
  // L2 it1: Y = X2'h(P3) * T0(P2) -> P0 hi
  mY = zero16();
  mac1<4, PP3, PP2>(mY, pA, pB);
  write_hi<PP0>(lds, wo, ev, mY);
  __syncthreads();
  // L2 bf16 iters 2..3: Y=P0, Z=P2, T=P1
#pragma unroll 1
  for (int it = 0; it < 2; ++it) {
    f32x16 a;
#pragma unroll
    for (int r = 0; r < 16; ++r) a[r] = -3.f * dmask[r];
    mac1<4, PP2, PP0>(a, pA, pB);
    f32x16 tv;
#pragma unroll
    for (int r = 0; r < 16; ++r) tv[r] = -0.5f * a[r];
    write_hi<PP1>(lds, wo, ev, tv);
    __syncthreads();
    mY = zero16();
    mac1<4, PP0, PP1>(mY, pA, pB);
    mZ = zero16();
    mac1<4, PP1, PP2>(mZ, pA, pB);
    __syncthreads();
    write_hi<PP0>(lds, wo, ev, mY);
    write_hi<PP2>(lds, wo, ev, mZ);
    __syncthreads();
  }
  // L2 restore: q16(Z); Y = X2'(P3/P4) * Zh(P2) -> split P0/P1
  q16x16(mZ);
  mY = zero16();
  mac2A<4, PP3, PP2>(mY, pA, pB);
  write_split<PP0>(lds, wo, ev, pl, mY, 0, 16);
  __syncthreads();
  // L2 delta4: D = 0.5(I - Zh*Ysplit) -> P3 hi (X2' dead)
  {
    f32x16 a;
#pragma unroll
    for (int r = 0; r < 16; ++r) a[r] = -dmask[r];
    mac2B<4, PP2, PP0>(a, pA, pB);
    f32x16 dv;
#pragma unroll
    for (int r = 0; r < 16; ++r) dv[r] = -0.5f * a[r];
    write_hi<PP3>(lds, wo, ev, dv);
  }
  __syncthreads();
  mac1<4, PP0, PP3>(mY, pA, pB);  // mY += Yh*D
  mac1<4, PP3, PP2>(mZ, pA, pB);  // mZ += D*Zh
  __syncthreads();
  write_split<PP0>(lds, wo, ev, pl, mY, 0, 16);
  q16x16(mZ);
  write_hi<PP2>(lds, wo, ev, mZ);
  __syncthreads();
  // L2 delta5 (masters final, no writeback)
  {
    f32x16 a;
#pragma unroll
    for (int r = 0; r < 16; ++r) a[r] = -dmask[r];
    mac2B<4, PP2, PP0>(a, pA, pB);
    f32x16 dv;
#pragma unroll
    for (int r = 0; r < 16; ++r) dv[r] = -0.5f * a[r];
    write_hi<PP3>(lds, wo, ev, dv);
  }
  __syncthreads();
  mac1<4, PP0, PP3>(mY, pA, pB);
  mac1<4, PP3, PP2>(mZ, pA, pB);
  // S = ca*Y - cb*Z -> split P0/P1
  f32x16 sv;
  {
    const float ca = 0.80141224f;  // 6.6^{1/4}/2
    const float cb = 0.31194493f;  // 1/(2*6.6^{1/4})
#pragma unroll
    for (int r = 0; r < 16; ++r) sv[r] = ca * mY[r] - cb * mZ[r];
  }
  __syncthreads();
  write_split<PP0>(lds, wo, ev, pl, sv, 0, 16);
  __syncthreads();
  // S2 = S*S (drop ll): S2h -> P2; q = A11*S2 + A9*I -> P3
  {
    f32x16 s2 = zero16();
    mac3<4, PP0, PP0>(s2, pA, pB);
    const float A11 = -0.08948864f, A9 = 0.12152778f;
    f32x16 qv;
#pragma unroll
    for (int r = 0; r < 16; ++r) qv[r] = A11 * s2[r] + A9 * dmask[r];
    write_hi<PP2>(lds, wo, ev, s2);
    write_hi<PP3>(lds, wo, ev, qv);
  }
  __syncthreads();
  // asinh Horner (bf16): 3 steps, q(P3)*S2(P2) + c*I -> P3
  {
    const float acoef[3] = {-0.17857143f, 0.3f, -0.66666667f};
#pragma unroll 1
    for (int j = 0; j < 3; ++j) {
      f32x16 a;
#pragma unroll
      for (int r = 0; r < 16; ++r) a[r] = acoef[j] * dmask[r];
      mac1<4, PP3, PP2>(a, pA, pB);
      __syncthreads();
      write_hi<PP3>(lds, wo, ev, a);
      __syncthreads();
    }
  }
  // q4 = q*S2 + 4I -> split P3/P4
  {
    f32x16 a;
#pragma unroll
    for (int r = 0; r < 16; ++r) a[r] = 4.f * dmask[r];
    mac1<4, PP3, PP2>(a, pA, pB);
    __syncthreads();
    write_split<PP3>(lds, wo, ev, pl, a, 0, 16);
    __syncthreads();
  }
  // L = S(P0/P1) * q4(P3/P4); pool DIRECTLY from regs -> x = P/2 split P0/P1
  {
    f32x16 mL = zero16();
    mac3<4, PP0, PP3>(mL, pA, pB);
    __syncthreads();  // all reads of P0..P4 done; safe to overwrite
#pragma unroll
    for (int q = 0; q < 8; ++q) {
      float rp = mL[2 * q] + mL[2 * q + 1];  // row-pair (in-lane)
      float p = 0.125f * (rp + dppswap(rp)); // col-pair (lane^1), /8 => P/2
      const int row = (R >> 1) + (q & 1) + 4 * (q >> 1) + 2 * half;
      const int colP = (Cc >> 1) + (ln31 >> 1);
      unsigned phw = cvtpk(p, p);
      float plo = p - __uint_as_float(phw << 16);
      unsigned plw = cvtpk(plo, plo);
      if (ev) {
        const int off =
            row * 128 + (((colP >> 3) ^ (row & 7)) << 4) + (colP & 7) * 2;
        *(short*)(lds + PP0 + off) = (short)phw;  // x hi
        *(short*)(lds + PP1 + off) = (short)plw;  // x lo
      }
    }
  }
  __syncthreads();
  // ===== exp(x) via Paterson-Stockmeyer, x = P/2 (32x32) =====
  // H = (c8 x4 + c7 x3 + c6 x2 + c5 x + c4 I) * x4 + (x3/6 + x2/2 + x + I)
  char* pE[2];
#pragma unroll
  for (int s = 0; s < 2; ++s) pE[s] = lds + swadr(ln31, 2 * s + half);
  f32x16 dmask2;
#pragma unroll
  for (int r = 0; r < 16; ++r)
    dmask2[r] = ((r & 3) + 8 * (r >> 2) + 4 * half == ln31) ? 1.f : 0.f;
  int wo2[16];
  {
    const int col0 = ln31 & ~1;
    const int cchunk = col0 >> 3, cbyte = (col0 & 7) * 2;
    const int rbase = 4 * half;
#pragma unroll
    for (int r = 0; r < 16; ++r) {
      const int m = rbase + (r & 3) + 8 * (r >> 2);
      wo2[r] = m * 128 + ((cchunk ^ (m & 7)) << 4) + cbyte;
    }
  }
  const int r0 = 4 * wv, r1 = 4 * wv + 4;  // this wave's write slice
  {
    // PHASE X2: x2 = x*x (dup); also fetch this wave's x-tile slice regs
    f32x16 x2a = zero16();
    mac3<2, PP0, PP0>(x2a, pE, pE);
    f32x16 xsv;
#pragma unroll
    for (int r = 0; r < 16; ++r) {
      xsv[r] = 0.f;
      if ((r >> 2) == wv) {  // uniform per wave, r compile-time
        const int rl = (r & 3) + 8 * (r >> 2) + 4 * half;
        const int off =
            rl * 128 + (((ln31 >> 3) ^ (rl & 7)) << 4) + (ln31 & 7) * 2;
        unsigned hb = *(const unsigned short*)(lds + PP0 + off);
        unsigned lb = *(const unsigned short*)(lds + PP1 + off);
        xsv[r] = __uint_as_float(hb << 16) + __uint_as_float(lb << 16);
      }
    }
    // P2/P3 dead since L-phase -> no barrier needed before this write
    write_split<PP2>(lds, wo2, ev, pl, x2a, r0, r1);
    __syncthreads();
    // PHASE X34: x3 = x2*x, x4 = x2*x2 (dup); form A,B combos in f32 regs
    f32x16 x3a = zero16();
    mac3<2, PP2, PP0>(x3a, pE, pE);
    f32x16 x4a = zero16();
    mac3<2, PP2, PP2>(x4a, pE, pE);
    const float c8 = 2.4801587e-5f;   // 1/40320
    const float c7 = 1.9841270e-4f;   // 1/5040
    const float c6 = 1.3888889e-3f;   // 1/720
    const float c5 = 8.3333333e-3f;   // 1/120
    const float c4 = 4.1666667e-2f;   // 1/24
    f32x16 Ac, Bc;
#pragma unroll
    for (int r = 0; r < 16; ++r) {
      Ac[r] = c8 * x4a[r] + c7 * x3a[r] + c6 * x2a[r] + c5 * xsv[r] +
              c4 * dmask2[r];
      Bc[r] = 0.16666667f * x3a[r] + 0.5f * x2a[r] + xsv[r] + dmask2[r];
    }
    __syncthreads();  // all waves done reading P0..P3
    write_split<PP0>(lds, wo2, ev, pl, x4a, r0, r1);  // x4 -> P0/P1 (x dead)
    write_split<PP2>(lds, wo2, ev, pl, Ac, r0, r1);   // A -> P2/P3 (x2 dead)
    __syncthreads();
    // PHASE U: H = A*x4 + B
    f32x16 Ha = zero16();
    mac3<2, PP2, PP0>(Ha, pE, pE);
#pragma unroll
    for (int r = 0; r < 16; ++r) Ha[r] += Bc[r];
    __syncthreads();  // U-mac reads of P0..P3 done
    write_split<PP2>(lds, wo2, ev, pl, Ha, r0, r1);   // H -> P2/P3
    __syncthreads();
  }
  // OUT = H*H -> global fp32
  {
    f32x16 acc = zero16();
    mac3<2, PP2, PP2>(acc, pE, pE);
    float* og = out + (size_t)blockIdx.x * 1024;
#pragma unroll
    for (int r = 0; r < 16; ++r) {
      if (r < r0 || r >= r1) continue;
      int rl = (r & 3) + 8 * (r >> 2) + 4 * half;
      og[rl * 32 + ln31] = acc[r];
    }
  }
}

extern "C" void kernel_launch(void* const* d_in, const int* in_sizes, int n_in,
                              void* d_out, int out_size, void* d_ws, size_t ws_size,
                              hipStream_t stream) {
  const float* X = (const float*)d_in[0];
  float* out = (float*)d_out;
  const int batch = in_sizes[0] / 4096;  // 8192
  spd_pool_kernel<<<batch, 256, 0, stream>>>(X, out);
}

// Round 9
// 470.289 us; speedup vs baseline: 1.4553x; 1.0231x over previous
//
#include <hip/hip_runtime.h>

typedef __attribute__((ext_vector_type(8))) short short8;
typedef __attribute__((ext_vector_type(16))) float f32x16;

// 5 planes of 8192 B (64 rows x 128 B). Split pairs = adjacent planes
// (lo = hi + 8192). Same-bank hi/lo pairing is only ever 2-way = free.
#define PL 8192
#define PP0 0
#define PP1 8192
#define PP2 16384
#define PP3 24576
#define PP4 32768

__device__ __forceinline__ int swadr(int m, int kc) {
  return m * 128 + ((kc ^ (m & 7)) << 4);
}

// packed f32->bf16 RNE (no builtin on gfx950)
__device__ __forceinline__ unsigned int cvtpk(float a, float b) {
  unsigned int r;
  asm("v_cvt_pk_bf16_f32 %0, %1, %2" : "=v"(r) : "v"(a), "v"(b));
  return r;
}
__device__ __forceinline__ float dppswap(float v) {  // lane ^ 1
  return __int_as_float(
      __builtin_amdgcn_mov_dpp(__float_as_int(v), 0xB1, 0xF, 0xF, true));
}
__device__ __forceinline__ f32x16 zero16() {
  f32x16 z;
#pragma unroll
  for (int i = 0; i < 16; ++i) z[i] = 0.f;
  return z;
}
__device__ __forceinline__ void q16x16(f32x16& v) {  // regs -> bf16 values
#pragma unroll
  for (int r = 0; r < 16; r += 2) {
    unsigned w = cvtpk(v[r], v[r + 1]);
    v[r] = __uint_as_float(w << 16);
    v[r + 1] = __uint_as_float(w & 0xFFFF0000u);
  }
}

// ---- init stores (thread-indexed) ----
__device__ __forceinline__ void store_hi8(char* dst, const float* v) {
  *(uint4*)dst = make_uint4(cvtpk(v[0], v[1]), cvtpk(v[2], v[3]),
                            cvtpk(v[4], v[5]), cvtpk(v[6], v[7]));
}
__device__ __forceinline__ void split_store8(char* dst, const float* v) {
  unsigned h[4], l[4];
#pragma unroll
  for (int j = 0; j < 4; ++j) {
    unsigned hw = cvtpk(v[2 * j], v[2 * j + 1]);
    float h0 = __uint_as_float(hw << 16);
    float h1 = __uint_as_float(hw & 0xFFFF0000u);
    l[j] = cvtpk(v[2 * j] - h0, v[2 * j + 1] - h1);
    h[j] = hw;
  }
  *(uint4*)dst = make_uint4(h[0], h[1], h[2], h[3]);
  *(uint4*)(dst + PL) = make_uint4(l[0], l[1], l[2], l[3]);
}

// ---- MFMA macs: per-lane base ptrs, plane select by template immediate.
// setprio(1) around the MFMA cluster (T5) — ONLY change vs the passing R6
// kernel; pure scheduler hint, cannot alter any byte written.
template <int NK, int OA, int OB, int N>
__device__ __forceinline__ void mac1(f32x16& acc, char* const (&pA)[N],
                                     char* const (&pB)[N]) {
  __builtin_amdgcn_s_setprio(1);
#pragma unroll
  for (int s = 0; s < NK; ++s) {
    short8 a = *(const short8*)(pA[s] + OA);
    short8 b = *(const short8*)(pB[s] + OB);
    acc = __builtin_amdgcn_mfma_f32_32x32x16_bf16(a, b, acc, 0, 0, 0);
  }
  __builtin_amdgcn_s_setprio(0);
}
template <int NK, int OA, int OB, int N>  // A split, B bf16
__device__ __forceinline__ void mac2A(f32x16& acc, char* const (&pA)[N],
                                      char* const (&pB)[N]) {
  __builtin_amdgcn_s_setprio(1);
#pragma unroll
  for (int s = 0; s < NK; ++s) {
    short8 ah = *(const short8*)(pA[s] + OA);
    short8 al = *(const short8*)(pA[s] + OA + PL);
    short8 b = *(const short8*)(pB[s] + OB);
    acc = __builtin_amdgcn_mfma_f32_32x32x16_bf16(ah, b, acc, 0, 0, 0);
    acc = __builtin_amdgcn_mfma_f32_32x32x16_bf16(al, b, acc, 0, 0, 0);
  }
  __builtin_amdgcn_s_setprio(0);
}
template <int NK, int OA, int OB, int N>  // A bf16, B split
__device__ __forceinline__ void mac2B(f32x16& acc, char* const (&pA)[N],
                                      char* const (&pB)[N]) {
  __builtin_amdgcn_s_setprio(1);
#pragma unroll
  for (int s = 0; s < NK; ++s) {
    short8 a = *(const short8*)(pA[s] + OA);
    short8 bh = *(const short8*)(pB[s] + OB);
    short8 bl = *(const short8*)(pB[s] + OB + PL);
    acc = __builtin_amdgcn_mfma_f32_32x32x16_bf16(a, bh, acc, 0, 0, 0);
    acc = __builtin_amdgcn_mfma_f32_32x32x16_bf16(a, bl, acc, 0, 0, 0);
  }
  __builtin_amdgcn_s_setprio(0);
}
template <int NK, int OA, int OB, int N>  // both split (drop lo*lo)
__device__ __forceinline__ void mac3(f32x16& acc, char* const (&pA)[N],
                                     char* const (&pB)[N]) {
  __builtin_amdgcn_s_setprio(1);
#pragma unroll
  for (int s = 0; s < NK; ++s) {
    short8 ah = *(const short8*)(pA[s] + OA);
    short8 al = *(const short8*)(pA[s] + OA + PL);
    short8 bh = *(const short8*)(pB[s] + OB);
    short8 bl = *(const short8*)(pB[s] + OB + PL);
    acc = __builtin_amdgcn_mfma_f32_32x32x16_bf16(ah, bh, acc, 0, 0, 0);
    acc = __builtin_amdgcn_mfma_f32_32x32x16_bf16(ah, bl, acc, 0, 0, 0);
    acc = __builtin_amdgcn_mfma_f32_32x32x16_bf16(al, bh, acc, 0, 0, 0);
  }
  __builtin_amdgcn_s_setprio(0);
}

// ---- C-tile writes: precomputed word offsets, DPP + cvt_pk packing ----
template <int OFF>
__device__ __forceinline__ void write_hi(char* lds, const int (&wo)[16], bool ev,
                                         const f32x16& vals) {
#pragma unroll
  for (int r = 0; r < 16; ++r) {
    float vn = dppswap(vals[r]);
    unsigned hw = cvtpk(vals[r], vn);
    if (ev) *(unsigned*)(lds + OFF + wo[r]) = hw;
  }
}
template <int OFF>
__device__ __forceinline__ void write_split(char* lds, const int (&wo)[16],
                                            bool ev, int pl, const f32x16& vals,
                                            int r0, int r1) {
#pragma unroll
  for (int r = 0; r < 16; ++r) {
    if (r < r0 || r >= r1) continue;
    float v = vals[r];
    float vn = dppswap(v);
    unsigned hw = cvtpk(v, vn);
    float lo = v - __uint_as_float(hw << 16);
    float lon = dppswap(lo);
    unsigned lw = cvtpk(lon, lo);
    *(unsigned*)(lds + OFF + pl + wo[r]) = ev ? hw : lw;
  }
}

__global__ void __launch_bounds__(256, 4)
spd_pool_kernel(const float* __restrict__ X, float* __restrict__ out) {
  __shared__ __align__(16) char lds[5 * 8192];  // 40960 B -> 4 blocks/CU

  const int tid = threadIdx.x;
  const int lane = tid & 63;
  const int wv = tid >> 6;
  const int R = (wv >> 1) * 32;
  const int Cc = (wv & 1) * 32;
  const int half = lane >> 5;
  const int ln31 = lane & 31;
  const bool ev = (ln31 & 1) == 0;
  const int pl = ev ? 0 : PL;

  // per-lane ds read base pointers; plane chosen by template imm
  char* pA[4];
  char* pB[4];
#pragma unroll
  for (int s = 0; s < 4; ++s) {
    const int kc = 2 * s + half;
    pA[s] = lds + swadr(R + ln31, kc);
    pB[s] = lds + swadr(Cc + ln31, kc);
  }
  // per-lane C-write word offsets (anchored at (R, Cc))
  int wo[16];
  {
    const int col0 = Cc + (ln31 & ~1);
    const int cchunk = col0 >> 3, cbyte = (col0 & 7) * 2;
    const int rbase = R + 4 * half;
#pragma unroll
    for (int r = 0; r < 16; ++r) {
      const int m = rbase + (r & 3) + 8 * (r >> 2);
      wo[r] = m * 128 + ((cchunk ^ (m & 7)) << 4) + cbyte;
    }
  }
  // diagonal mask of this thread's C fragment
  f32x16 dmask;
#pragma unroll
  for (int r = 0; r < 16; ++r)
    dmask[r] = (R + (r & 3) + 8 * (r >> 2) + 4 * half == Cc + ln31) ? 1.f : 0.f;

  f32x16 mY, mZ;

  // ======= init: P0/P1 = X' = X/6.6 (split); P2 = T0 =======
  {
    const int em = tid >> 2;
    const int ekc = (tid & 3) * 2;
    const int ec0 = ekc * 8;
    const float ic1 = 1.0f / 6.6f;
    const float* Xg = X + (size_t)blockIdx.x * 4096 + em * 64 + ec0;
    const float4* xp = (const float4*)Xg;
    float4 a = xp[0], b = xp[1], c = xp[2], d = xp[3];
    float v[16] = {a.x * ic1, a.y * ic1, a.z * ic1, a.w * ic1,
                   b.x * ic1, b.y * ic1, b.z * ic1, b.w * ic1,
                   c.x * ic1, c.y * ic1, c.z * ic1, c.w * ic1,
                   d.x * ic1, d.y * ic1, d.z * ic1, d.w * ic1};
    float t[16];
#pragma unroll
    for (int i = 0; i < 16; ++i)
      t[i] = ((em == ec0 + i) ? 1.5f : 0.f) - 0.5f * v[i];
    split_store8(lds + PP0 + swadr(em, ekc), v);
    split_store8(lds + PP0 + swadr(em, ekc + 1), v + 8);
    store_hi8(lds + PP2 + swadr(em, ekc), t);
    store_hi8(lds + PP2 + swadr(em, ekc + 1), t + 8);
  }
  __syncthreads();
  // L1 it1: Y = X'h(P0) * T0(P2) -> P3 hi
  mY = zero16();
  mac1<4, PP0, PP2>(mY, pA, pB);
  write_hi<PP3>(lds, wo, ev, mY);
  __syncthreads();
  // L1 bf16 iters 2..5: Z=P2, Y=P3, T=P4
#pragma unroll 1
  for (int it = 0; it < 4; ++it) {
    f32x16 a;
#pragma unroll
    for (int r = 0; r < 16; ++r) a[r] = -3.f * dmask[r];
    mac1<4, PP2, PP3>(a, pA, pB);
    f32x16 tv;
#pragma unroll
    for (int r = 0; r < 16; ++r) tv[r] = -0.5f * a[r];
    write_hi<PP4>(lds, wo, ev, tv);
    __syncthreads();
    mY = zero16();
    mac1<4, PP3, PP4>(mY, pA, pB);
    mZ = zero16();
    mac1<4, PP4, PP2>(mZ, pA, pB);
    __syncthreads();
    write_hi<PP3>(lds, wo, ev, mY);
    write_hi<PP2>(lds, wo, ev, mZ);
    __syncthreads();
  }
  // L1 restore: mY = X'(split P0/P1) * Zh(P2) -> split P3/P4
  mY = zero16();
  mac2A<4, PP0, PP2>(mY, pA, pB);
  write_split<PP3>(lds, wo, ev, pl, mY, 0, 16);
  __syncthreads();
  // L1 delta (Y only): D = 0.5(I - Zh*Ysplit) -> P0 hi (X' dead)
  {
    f32x16 a;
#pragma unroll
    for (int r = 0; r < 16; ++r) a[r] = -dmask[r];
    mac2B<4, PP2, PP3>(a, pA, pB);
    f32x16 dv;
#pragma unroll
    for (int r = 0; r < 16; ++r) dv[r] = -0.5f * a[r];
    write_hi<PP0>(lds, wo, ev, dv);
  }
  __syncthreads();
  mac1<4, PP3, PP0>(mY, pA, pB);  // mY += Yh*D
  __syncthreads();
  write_split<PP3>(lds, wo, ev, pl, mY, 0, 16);  // X2' -> P3/P4
  {
    f32x16 t0v;
#pragma unroll
    for (int r = 0; r < 16; ++r) t0v[r] = 1.5f * dmask[r] - 0.5f * mY[r];
    write_hi<PP2>(lds, wo, ev, t0v);  // T0 -> P2
  }
  __syncthreads();
  // L2 it1: Y = X2'h(P3) * T0(P2) -> P0 hi
  mY = zero16();
  mac1<4, PP3, PP2>(mY, pA, pB);
  write_hi<PP0>(lds, wo, ev, mY);
  __syncthreads();
  // L2 bf16 iters 2..3: Y=P0, Z=P2, T=P1
#pragma unroll 1
  for (int it = 0; it < 2; ++it) {
    f32x16 a;
#pragma unroll
    for (int r = 0; r < 16; ++r) a[r] = -3.f * dmask[r];
    mac1<4, PP2, PP0>(a, pA, pB);
    f32x16 tv;
#pragma unroll
    for (int r = 0; r < 16; ++r) tv[r] = -0.5f * a[r];
    write_hi<PP1>(lds, wo, ev, tv);
    __syncthreads();
    mY = zero16();
    mac1<4, PP0, PP1>(mY, pA, pB);
    mZ = zero16();
    mac1<4, PP1, PP2>(mZ, pA, pB);
    __syncthreads();
    write_hi<PP0>(lds, wo, ev, mY);
    write_hi<PP2>(lds, wo, ev, mZ);
    __syncthreads();
  }
  // L2 restore: q16(Z); Y = X2'(P3/P4) * Zh(P2) -> split P0/P1
  q16x16(mZ);
  mY = zero16();
  mac2A<4, PP3, PP2>(mY, pA, pB);
  write_split<PP0>(lds, wo, ev, pl, mY, 0, 16);
  __syncthreads();
  // L2 delta4: D = 0.5(I - Zh*Ysplit) -> P3 hi (X2' dead)
  {
    f32x16 a;
#pragma unroll
    for (int r = 0; r < 16; ++r) a[r] = -dmask[r];
    mac2B<4, PP2, PP0>(a, pA, pB);
    f32x16 dv;
#pragma unroll
    for (int r = 0; r < 16; ++r) dv[r] = -0.5f * a[r];
    write_hi<PP3>(lds, wo, ev, dv);
  }
  __syncthreads();
  mac1<4, PP0, PP3>(mY, pA, pB);  // mY += Yh*D
  mac1<4, PP3, PP2>(mZ, pA, pB);  // mZ += D*Zh
  __syncthreads();
  write_split<PP0>(lds, wo, ev, pl, mY, 0, 16);
  q16x16(mZ);
  write_hi<PP2>(lds, wo, ev, mZ);
  __syncthreads();
  // L2 delta5 (masters final, no writeback)
  {
    f32x16 a;
#pragma unroll
    for (int r = 0; r < 16; ++r) a[r] = -dmask[r];
    mac2B<4, PP2, PP0>(a, pA, pB);
    f32x16 dv;
#pragma unroll
    for (int r = 0; r < 16; ++r) dv[r] = -0.5f * a[r];
    write_hi<PP3>(lds, wo, ev, dv);
  }
  __syncthreads();
  mac1<4, PP0, PP3>(mY, pA, pB);
  mac1<4, PP3, PP2>(mZ, pA, pB);
  // S = ca*Y - cb*Z -> split P0/P1
  f32x16 sv;
  {
    const float ca = 0.80141224f;  // 6.6^{1/4}/2
    const float cb = 0.31194493f;  // 1/(2*6.6^{1/4})
#pragma unroll
    for (int r = 0; r < 16; ++r) sv[r] = ca * mY[r] - cb * mZ[r];
  }
  __syncthreads();
  write_split<PP0>(lds, wo, ev, pl, sv, 0, 16);
  __syncthreads();
  // S2 = S*S (drop ll): S2h -> P2; q = A11*S2 + A9*I -> P3
  {
    f32x16 s2 = zero16();
    mac3<4, PP0, PP0>(s2, pA, pB);
    const float A11 = -0.08948864f, A9 = 0.12152778f;
    f32x16 qv;
#pragma unroll
    for (int r = 0; r < 16; ++r) qv[r] = A11 * s2[r] + A9 * dmask[r];
    write_hi<PP2>(lds, wo, ev, s2);
    write_hi<PP3>(lds, wo, ev, qv);
  }
  __syncthreads();
  // asinh Horner (bf16): 3 steps, q(P3)*S2(P2) + c*I -> P3
  {
    const float acoef[3] = {-0.17857143f, 0.3f, -0.66666667f};
#pragma unroll 1
    for (int j = 0; j < 3; ++j) {
      f32x16 a;
#pragma unroll
      for (int r = 0; r < 16; ++r) a[r] = acoef[j] * dmask[r];
      mac1<4, PP3, PP2>(a, pA, pB);
      __syncthreads();
      write_hi<PP3>(lds, wo, ev, a);
      __syncthreads();
    }
  }
  // q4 = q*S2 + 4I -> split P3/P4
  {
    f32x16 a;
#pragma unroll
    for (int r = 0; r < 16; ++r) a[r] = 4.f * dmask[r];
    mac1<4, PP3, PP2>(a, pA, pB);
    __syncthreads();
    write_split<PP3>(lds, wo, ev, pl, a, 0, 16);
    __syncthreads();
  }
  // L = S(P0/P1) * q4(P3/P4); pool DIRECTLY from regs -> x = P/2 split P0/P1
  {
    f32x16 mL = zero16();
    mac3<4, PP0, PP3>(mL, pA, pB);
    __syncthreads();  // all reads of P0..P4 done; safe to overwrite
#pragma unroll
    for (int q = 0; q < 8; ++q) {
      float rp = mL[2 * q] + mL[2 * q + 1];  // row-pair (in-lane)
      float p = 0.125f * (rp + dppswap(rp)); // col-pair (lane^1), /8 => P/2
      const int row = (R >> 1) + (q & 1) + 4 * (q >> 1) + 2 * half;
      const int colP = (Cc >> 1) + (ln31 >> 1);
      unsigned phw = cvtpk(p, p);
      float plo = p - __uint_as_float(phw << 16);
      unsigned plw = cvtpk(plo, plo);
      if (ev) {
        const int off =
            row * 128 + (((colP >> 3) ^ (row & 7)) << 4) + (colP & 7) * 2;
        *(short*)(lds + PP0 + off) = (short)phw;  // x hi
        *(short*)(lds + PP1 + off) = (short)plw;  // x lo
      }
    }
  }
  __syncthreads();
  // ===== exp(x) via Paterson-Stockmeyer, x = P/2 (32x32) =====
  // H = (c8 x4 + c7 x3 + c6 x2 + c5 x + c4 I) * x4 + (x3/6 + x2/2 + x + I)
  char* pE[2];
#pragma unroll
  for (int s = 0; s < 2; ++s) pE[s] = lds + swadr(ln31, 2 * s + half);
  f32x16 dmask2;
#pragma unroll
  for (int r = 0; r < 16; ++r)
    dmask2[r] = ((r & 3) + 8 * (r >> 2) + 4 * half == ln31) ? 1.f : 0.f;
  int wo2[16];
  {
    const int col0 = ln31 & ~1;
    const int cchunk = col0 >> 3, cbyte = (col0 & 7) * 2;
    const int rbase = 4 * half;
#pragma unroll
    for (int r = 0; r < 16; ++r) {
      const int m = rbase + (r & 3) + 8 * (r >> 2);
      wo2[r] = m * 128 + ((cchunk ^ (m & 7)) << 4) + cbyte;
    }
  }
  const int r0 = 4 * wv, r1 = 4 * wv + 4;  // this wave's write slice
  {
    // PHASE X2: x2 = x*x (dup); also fetch this wave's x-tile slice regs
    f32x16 x2a = zero16();
    mac3<2, PP0, PP0>(x2a, pE, pE);
    f32x16 xsv;
#pragma unroll
    for (int r = 0; r < 16; ++r) {
      xsv[r] = 0.f;
      if ((r >> 2) == wv) {  // uniform per wave, r compile-time
        const int rl = (r & 3) + 8 * (r >> 2) + 4 * half;
        const int off =
            rl * 128 + (((ln31 >> 3) ^ (rl & 7)) << 4) + (ln31 & 7) * 2;
        unsigned hb = *(const unsigned short*)(lds + PP0 + off);
        unsigned lb = *(const unsigned short*)(lds + PP1 + off);
        xsv[r] = __uint_as_float(hb << 16) + __uint_as_float(lb << 16);
      }
    }
    // P2/P3 dead since L-phase -> no barrier needed before this write
    write_split<PP2>(lds, wo2, ev, pl, x2a, r0, r1);
    __syncthreads();
    // PHASE X34: x3 = x2*x, x4 = x2*x2 (dup); form A,B combos in f32 regs
    f32x16 x3a = zero16();
    mac3<2, PP2, PP0>(x3a, pE, pE);
    f32x16 x4a = zero16();
    mac3<2, PP2, PP2>(x4a, pE, pE);
    const float c8 = 2.4801587e-5f;   // 1/40320
    const float c7 = 1.9841270e-4f;   // 1/5040
    const float c6 = 1.3888889e-3f;   // 1/720
    const float c5 = 8.3333333e-3f;   // 1/120
    const float c4 = 4.1666667e-2f;   // 1/24
    f32x16 Ac, Bc;
#pragma unroll
    for (int r = 0; r < 16; ++r) {
      Ac[r] = c8 * x4a[r] + c7 * x3a[r] + c6 * x2a[r] + c5 * xsv[r] +
              c4 * dmask2[r];
      Bc[r] = 0.16666667f * x3a[r] + 0.5f * x2a[r] + xsv[r] + dmask2[r];
    }
    __syncthreads();  // all waves done reading P0..P3
    write_split<PP0>(lds, wo2, ev, pl, x4a, r0, r1);  // x4 -> P0/P1 (x dead)
    write_split<PP2>(lds, wo2, ev, pl, Ac, r0, r1);   // A -> P2/P3 (x2 dead)
    __syncthreads();
    // PHASE U: H = A*x4 + B
    f32x16 Ha = zero16();
    mac3<2, PP2, PP0>(Ha, pE, pE);
#pragma unroll
    for (int r = 0; r < 16; ++r) Ha[r] += Bc[r];
    __syncthreads();  // U-mac reads of P0..P3 done
    write_split<PP2>(lds, wo2, ev, pl, Ha, r0, r1);   // H -> P2/P3
    __syncthreads();
  }
  // OUT = H*H -> global fp32
  {
    f32x16 acc = zero16();
    mac3<2, PP2, PP2>(acc, pE, pE);
    float* og = out + (size_t)blockIdx.x * 1024;
#pragma unroll
    for (int r = 0; r < 16; ++r) {
      if (r < r0 || r >= r1) continue;
      int rl = (r & 3) + 8 * (r >> 2) + 4 * half;
      og[rl * 32 + ln31] = acc[r];
    }
  }
}

extern "C" void kernel_launch(void* const* d_in, const int* in_sizes, int n_in,
                              void* d_out, int out_size, void* d_ws, size_t ws_size,
                              hipStream_t stream) {
  const float* X = (const float*)d_in[0];
  float* out = (float*)d_out;
  const int batch = in_sizes[0] / 4096;  // 8192
  spd_pool_kernel<<<batch, 256, 0, stream>>>(X, out);
}